// Round 2
// baseline (803.191 us; speedup 1.0000x reference)
//
#include <hip/hip_runtime.h>
#include <hip/hip_bf16.h>
#include <stdint.h>

// ObjectDetectionLoss (SSD MultiBox) — MI355X / gfx950
// B=64, N=16800, C=21. Output: 3 fp32 scalars.
//
// Pipeline:
//   memset(2.1 MB accum region)
//   K1 k_perdata (4200x256): sl1/ce per anchor, ce_neg store, 12-bit IEEE-bin
//      histogram (count + f32 sum) per batch, per-batch pos stats.
//   K2 k_scan    (64x1024):  suffix-scan 4096 bins -> boundary bin, r, strict fp64 sum.
//   K3 k_cand    (4200x256): append boundary-bin values to cand[b].
//   K4 k_sel     (64x256):   exact radix select of low 20 bits among candidates,
//                            boundary sum = sum(v>T) + r*T; per-batch finals.
//   K5 k_final   (1x64):     reduce over batches -> 3 outputs.

#define NB 64
#define NN 16800
#define NC 21
#define CAP 4096
#define FP32_EPS_F 1.1920928955078125e-07f

// ---------------- workspace layout (bytes from ws base) ----------------
#define OFF_HIST     0u          // uint32 [64*4096]  1 MB
#define OFF_HISTSUM  1048576u    // float  [64*4096]  1 MB
#define OFF_STRICT   2097152u    // double [64]
#define OFF_FLB      2097664u    // double [64]
#define OFF_FLL      2098176u    // double [64]
#define OFF_CANDCNT  2098688u    // uint32 [64]
#define OFF_ACCPOS   2098944u    // uint32 [64]
#define OFF_ACCSL1   2099200u    // float  [64]
#define OFF_ACCCE    2099456u    // float  [64]
#define OFF_T12      2099712u    // uint32 [64]
#define OFF_RREM     2099968u    // int32  [64]
#define OFF_FPN      2100224u    // int32  [64]
#define MEMSET_BYTES 2100480u
#define OFF_CENEG    2101248u    // float  [NB*NN]   4.30 MB
#define OFF_CAND     6402048u    // uint32 [64*CAP]  1 MB   (total ~7.1 MB)

// ===================== K1: per-anchor =====================
__global__ __launch_bounds__(256) void k_perdata(
    const float* __restrict__ p_bboxs, const float* __restrict__ g_bboxs,
    const float* __restrict__ p_labels, const int* __restrict__ g_labels,
    const float* __restrict__ ancs,
    float* __restrict__ ce_neg, uint32_t* __restrict__ hist,
    float* __restrict__ histsum, uint32_t* __restrict__ acc_pos,
    float* __restrict__ acc_sl1, float* __restrict__ acc_ce)
{
    __shared__ float lab[256 * NC];            // 21504 B
    __shared__ float s_sl1[2], s_ce[2];
    __shared__ uint32_t s_pos[2];

    const int tid = threadIdx.x;
    const int base = blockIdx.x * 256;

    if (tid < 2) { s_sl1[tid] = 0.f; s_ce[tid] = 0.f; s_pos[tid] = 0u; }

    // stage p_labels tile, fully coalesced float4 (21504 B/block, 16B-aligned)
    {
        const float4* src = (const float4*)(p_labels + (size_t)base * NC);
        float4* dst = (float4*)lab;
        constexpr int NV = 256 * NC / 4;       // 1344
        for (int j = tid; j < NV; j += 256) dst[j] = src[j];
    }
    __syncthreads();

    const int idx = base + tid;
    const int b = idx / NN;
    const int n = idx - b * NN;

    const float4 p = ((const float4*)p_bboxs)[idx];
    const float4 g = ((const float4*)g_bboxs)[idx];
    const float4 a = ((const float4*)ancs)[n];
    const int gl = g_labels[idx];

    // regression targets + SmoothL1 (beta=1), summed over 4 coords
    const float tx = 10.0f * (g.x - a.x) / a.z;
    const float ty = 10.0f * (g.y - a.y) / a.w;
    const float tw = 5.0f * __logf(g.z / a.z);
    const float th = 5.0f * __logf(g.w / a.w);
    float sl1 = 0.f;
    {
        float d, ad;
        d = p.x - tx; ad = fabsf(d); sl1 += (ad < 1.f) ? 0.5f * d * d : ad - 0.5f;
        d = p.y - ty; ad = fabsf(d); sl1 += (ad < 1.f) ? 0.5f * d * d : ad - 0.5f;
        d = p.z - tw; ad = fabsf(d); sl1 += (ad < 1.f) ? 0.5f * d * d : ad - 0.5f;
        d = p.w - th; ad = fabsf(d); sl1 += (ad < 1.f) ? 0.5f * d * d : ad - 0.5f;
    }

    // cross entropy: lse - x[gl]
    const float* row = lab + tid * NC;         // stride 21 (odd) -> 2-way LDS alias, free
    float m = row[0];
    #pragma unroll
    for (int c = 1; c < NC; ++c) m = fmaxf(m, row[c]);
    float s = 0.f;
    #pragma unroll
    for (int c = 0; c < NC; ++c) s += __expf(row[c] - m);
    const float lse = m + __logf(s);
    const float ce = fmaxf(lse - row[gl], 0.f);   // >=0, bits order-monotonic

    const bool pos = gl > 0;
    const float ce_store = pos ? 0.f : ce;
    ce_neg[idx] = ce_store;                    // coalesced

    // 12-bit IEEE-bin histogram (count + value-sum)
    const uint32_t bin = __float_as_uint(ce_store) >> 20;
    atomicAdd(&hist[((uint32_t)b << 12) + bin], 1u);
    if (ce_store > 0.f)
        unsafeAtomicAdd(&histsum[((uint32_t)b << 12) + bin], ce_store);

    // per-batch positive stats via LDS atomics (~5 pos threads / block)
    const int b0 = base / NN;
    if (pos) {
        const int seg = b - b0;                // 0 or 1 (block spans <=2 batches)
        atomicAdd(&s_pos[seg], 1u);
        atomicAdd(&s_sl1[seg], sl1);
        atomicAdd(&s_ce[seg], ce);
    }
    __syncthreads();
    if (tid == 0) {
        if (s_pos[0]) {
            atomicAdd(&acc_pos[b0], s_pos[0]);
            unsafeAtomicAdd(&acc_sl1[b0], s_sl1[0]);
            unsafeAtomicAdd(&acc_ce[b0], s_ce[0]);
        }
        if (s_pos[1]) {
            atomicAdd(&acc_pos[b0 + 1], s_pos[1]);
            unsafeAtomicAdd(&acc_sl1[b0 + 1], s_sl1[1]);
            unsafeAtomicAdd(&acc_ce[b0 + 1], s_ce[1]);
        }
    }
}

// ===================== K2: per-batch 4096-bin suffix scan =====================
__global__ __launch_bounds__(1024) void k_scan(
    const uint32_t* __restrict__ hist, const float* __restrict__ histsum,
    const uint32_t* __restrict__ acc_pos,
    uint32_t* __restrict__ t12, int* __restrict__ rrem, double* __restrict__ strict)
{
    __shared__ uint32_t wC[16]; __shared__ double wS[16];
    __shared__ uint32_t oC[16]; __shared__ double oS[16];

    const int tid = threadIdx.x, lane = tid & 63, wid = tid >> 6;
    const int b = blockIdx.x;
    const uint32_t hb = (uint32_t)b << 12;

    // each thread: 4 bins in DESCENDING value order
    uint32_t c4[4]; float s4[4];
    uint32_t cnt = 0; double sum = 0.0;
    #pragma unroll
    for (int j = 0; j < 4; ++j) {
        const uint32_t bin = 4095u - (uint32_t)(4 * tid + j);
        c4[j] = hist[hb + bin];
        s4[j] = histsum[hb + bin];
        cnt += c4[j]; sum += (double)s4[j];
    }

    // inclusive wave scan
    uint32_t ic = cnt; double is = sum;
    #pragma unroll
    for (int off = 1; off < 64; off <<= 1) {
        const uint32_t tc = __shfl_up(ic, off);
        const double   ts = __shfl_up(is, off);
        if (lane >= off) { ic += tc; is += ts; }
    }
    if (lane == 63) { wC[wid] = ic; wS[wid] = is; }
    __syncthreads();
    if (tid == 0) {
        uint32_t rc = 0; double rs = 0.0;
        for (int w = 0; w < 16; ++w) { oC[w] = rc; oS[w] = rs; rc += wC[w]; rs += wS[w]; }
    }
    __syncthreads();
    const uint32_t exC = oC[wid] + ic - cnt;   // exclusive prefix (desc order)
    const double   exS = oS[wid] + is - sum;

    int k = 3 * (int)acc_pos[b];               // NEG_RATIO
    if (k > NN) k = NN;
    if (k < 1) k = 1;                          // pos=0 handled by mask in k_final

    if ((int)exC < k && k <= (int)(exC + cnt)) {
        int need = k - (int)exC;
        double st = exS;
        #pragma unroll
        for (int j = 0; j < 4; ++j) {
            const int c = (int)c4[j];
            if (need <= c) {
                t12[b] = 4095u - (uint32_t)(4 * tid + j);
                rrem[b] = need;
                strict[b] = st;                // fp64 sum of all bins strictly above
                break;
            }
            need -= c; st += (double)s4[j];
        }
    }
}

// ===================== K3: boundary-bin candidate collection =====================
__global__ __launch_bounds__(256) void k_cand(
    const float* __restrict__ ce_neg, const uint32_t* __restrict__ t12,
    uint32_t* __restrict__ candcnt, uint32_t* __restrict__ cand)
{
    const int idx = blockIdx.x * 256 + threadIdx.x;
    const int b = idx / NN;
    const uint32_t v = __float_as_uint(ce_neg[idx]);
    if ((v >> 20) == t12[b]) {
        const uint32_t p = atomicAdd(&candcnt[b], 1u);
        if (p < CAP) cand[((uint32_t)b << 12) + p] = v;
    }
}

// ===================== K4: exact select among candidates + finals =====================
__global__ __launch_bounds__(256) void k_sel(
    const uint32_t* __restrict__ cand, const uint32_t* __restrict__ candcnt,
    const uint32_t* __restrict__ acc_pos, const float* __restrict__ acc_sl1,
    const float* __restrict__ acc_ce, const uint32_t* __restrict__ t12,
    const int* __restrict__ rrem, const double* __restrict__ strict,
    double* __restrict__ flb, double* __restrict__ fll, int* __restrict__ fpn)
{
    __shared__ uint32_t sv[CAP];               // 16 KB
    __shared__ uint32_t h[256];
    __shared__ int s_need;
    __shared__ uint32_t s_cur, s_mask;
    __shared__ double part[4];

    const int tid = threadIdx.x, lane = tid & 63;
    const int b = blockIdx.x;

    int cnt = (int)candcnt[b]; if (cnt > CAP) cnt = CAP;
    for (int i = tid; i < cnt; i += 256) sv[i] = cand[((uint32_t)b << 12) + i];
    if (tid == 0) {
        int nd = rrem[b]; if (nd > cnt) nd = cnt;
        s_need = nd;
        s_cur = t12[b] << 20;
        s_mask = 0xFFF00000u;
    }
    __syncthreads();

    // exact radix select over low 20 bits: (shift,bins) = (12,256),(4,256),(0,16)
    #pragma unroll
    for (int p = 0; p < 3; ++p) {
        const int sh = (p == 0) ? 12 : (p == 1) ? 4 : 0;
        const uint32_t nb = (p == 2) ? 16u : 256u;
        h[tid] = 0u;
        __syncthreads();
        const uint32_t cur = s_cur, msk = s_mask, bm = nb - 1u;
        for (int i = tid; i < cnt; i += 256) {
            const uint32_t v = sv[i];
            if ((v & msk) == cur) atomicAdd(&h[(v >> sh) & bm], 1u);
        }
        __syncthreads();
        if (tid == 0) {
            int need = s_need;
            for (int d = (int)nb - 1; d >= 0; --d) {
                const int c = (int)h[d];
                if (need <= c) { s_cur = cur | ((uint32_t)d << sh); s_need = need; break; }
                need -= c;
            }
            s_mask = msk | (bm << sh);
        }
        __syncthreads();
    }

    const uint32_t T = s_cur;                  // exact k-th largest bits
    const int rf = s_need;                     // #values == T to include

    double loc = 0.0;
    for (int i = tid; i < cnt; i += 256) {
        const uint32_t v = sv[i];
        if (v > T) loc += (double)__uint_as_float(v);
    }
    #pragma unroll
    for (int off = 32; off > 0; off >>= 1) loc += __shfl_down(loc, off);
    if (lane == 0) part[tid >> 6] = loc;
    __syncthreads();
    if (tid == 0) {
        const double bound = part[0] + part[1] + part[2] + part[3]
                           + (double)rf * (double)__uint_as_float(T);
        flb[b] = (double)acc_sl1[b];
        fll[b] = (double)acc_ce[b] + strict[b] + bound;
        fpn[b] = (int)acc_pos[b];
    }
}

// ===================== K5: final reduction over B =====================
__global__ __launch_bounds__(64) void k_final(
    const double* __restrict__ flb, const double* __restrict__ fll,
    const int* __restrict__ fpn, float* __restrict__ out)
{
    const int t = threadIdx.x;                 // 64 == NB
    const double lb = flb[t];
    const double ll = fll[t];
    const int pn = fpn[t];
    const double nm = (pn > 0) ? 1.0 : 0.0;
    const float pf = fmaxf((float)pn, FP32_EPS_F);
    const double inv = nm / (double)pf;
    double tb = lb * inv;
    double tl = ll * inv;
    double tt = tb + tl;                       // COEFF = (1,1)
    #pragma unroll
    for (int off = 32; off > 0; off >>= 1) {
        tt += __shfl_down(tt, off);
        tb += __shfl_down(tb, off);
        tl += __shfl_down(tl, off);
    }
    if (t == 0) {
        out[0] = (float)(tt / (double)NB);
        out[1] = (float)(tb / (double)NB);
        out[2] = (float)(tl / (double)NB);
    }
}

// ===================== launcher =====================
extern "C" void kernel_launch(void* const* d_in, const int* in_sizes, int n_in,
                              void* d_out, int out_size, void* d_ws, size_t ws_size,
                              hipStream_t stream)
{
    const float* p_bboxs  = (const float*)d_in[0];
    const float* g_bboxs  = (const float*)d_in[1];
    const float* p_labels = (const float*)d_in[2];
    const int*   g_labels = (const int*)d_in[3];
    const float* ancs     = (const float*)d_in[4];
    float* out = (float*)d_out;

    char* ws = (char*)d_ws;
    uint32_t* hist    = (uint32_t*)(ws + OFF_HIST);
    float*    histsum = (float*)   (ws + OFF_HISTSUM);
    double*   strictv = (double*)  (ws + OFF_STRICT);
    double*   flb     = (double*)  (ws + OFF_FLB);
    double*   fll     = (double*)  (ws + OFF_FLL);
    uint32_t* candcnt = (uint32_t*)(ws + OFF_CANDCNT);
    uint32_t* acc_pos = (uint32_t*)(ws + OFF_ACCPOS);
    float*    acc_sl1 = (float*)   (ws + OFF_ACCSL1);
    float*    acc_ce  = (float*)   (ws + OFF_ACCCE);
    uint32_t* t12     = (uint32_t*)(ws + OFF_T12);
    int*      rrem    = (int*)     (ws + OFF_RREM);
    int*      fpn     = (int*)     (ws + OFF_FPN);
    float*    ce_neg  = (float*)   (ws + OFF_CENEG);
    uint32_t* cand    = (uint32_t*)(ws + OFF_CAND);

    hipMemsetAsync(ws, 0, MEMSET_BYTES, stream);

    k_perdata<<<(NB * NN) / 256, 256, 0, stream>>>(
        p_bboxs, g_bboxs, p_labels, g_labels, ancs,
        ce_neg, hist, histsum, acc_pos, acc_sl1, acc_ce);

    k_scan<<<NB, 1024, 0, stream>>>(hist, histsum, acc_pos, t12, rrem, strictv);

    k_cand<<<(NB * NN) / 256, 256, 0, stream>>>(ce_neg, t12, candcnt, cand);

    k_sel<<<NB, 256, 0, stream>>>(cand, candcnt, acc_pos, acc_sl1, acc_ce,
                                  t12, rrem, strictv, flb, fll, fpn);

    k_final<<<1, 64, 0, stream>>>(flb, fll, fpn, out);
}

// Round 3
// 222.034 us; speedup vs baseline: 3.6174x; 3.6174x over previous
//
#include <hip/hip_runtime.h>
#include <hip/hip_bf16.h>
#include <stdint.h>

// ObjectDetectionLoss (SSD MultiBox) — MI355X / gfx950
// B=64, N=16800, C=21. Output: 3 fp32 scalars.
//
// Zero global atomics anywhere (round-2 lesson: hot-line device atomics
// serialize at ~6.5ns/op; 64K of them = 417us).
//
// Pipeline:
//   K1 k_perdata (4200x256): sl1/ce per anchor -> ce_neg store; per-block
//      pos stats via LDS -> plain stores to partial[block] (2 segments).
//   K2 k_select  (64x1024): per batch: reduce partials; load 16800 CE bits
//      to LDS + private 4096-bin histogram (top-12 IEEE bits); suffix scan
//      -> boundary bin + rank; 3-pass radix refine (low 20 bits) -> exact
//      k-th value T; sum(v>T) + r*T (tie-exact); per-batch finals.
//   K3 k_final   (1x64): reduce over batches -> 3 outputs.

#define NB 64
#define NN 16800
#define NC 21
#define NBLK1 ((NB * NN) / 256)   // 4200, exact
#define FP32_EPS_F 1.1920928955078125e-07f

// ---------------- workspace layout (bytes) ----------------
#define OFF_PARTIAL 0u            // float4 [2*4200] = 134400 B (plain stores)
#define OFF_FLB     134400u       // double [64]
#define OFF_FLL     134912u       // double [64]
#define OFF_FPN     135424u       // int    [64]
#define OFF_CENEG   135680u       // float  [NB*NN] = 4.3 MB

// ===================== K1: per-anchor =====================
__global__ __launch_bounds__(256) void k_perdata(
    const float* __restrict__ p_bboxs, const float* __restrict__ g_bboxs,
    const float* __restrict__ p_labels, const int* __restrict__ g_labels,
    const float* __restrict__ ancs,
    float* __restrict__ ce_neg, float4* __restrict__ partial)
{
    __shared__ float lab[256 * NC];            // 21504 B
    __shared__ float st[8];                    // [seg0|seg1] x {pos,sl1,ce,pad}

    const int tid = threadIdx.x;
    const int base = blockIdx.x * 256;

    if (tid < 8) st[tid] = 0.f;

    // stage p_labels tile, fully coalesced float4 (21504 B/block, 16B-aligned)
    {
        const float4* src = (const float4*)(p_labels + (size_t)base * NC);
        float4* dst = (float4*)lab;
        constexpr int NV = 256 * NC / 4;       // 1344
        for (int j = tid; j < NV; j += 256) dst[j] = src[j];
    }
    __syncthreads();

    const int idx = base + tid;
    const int b = idx / NN;
    const int n = idx - b * NN;
    const int b0 = base / NN;

    const float4 p = ((const float4*)p_bboxs)[idx];
    const float4 g = ((const float4*)g_bboxs)[idx];
    const float4 a = ((const float4*)ancs)[n];
    const int gl = g_labels[idx];

    // regression targets + SmoothL1 (beta=1), summed over 4 coords
    const float tx = 10.0f * (g.x - a.x) / a.z;
    const float ty = 10.0f * (g.y - a.y) / a.w;
    const float tw = 5.0f * __logf(g.z / a.z);
    const float th = 5.0f * __logf(g.w / a.w);
    float sl1 = 0.f;
    {
        float d, ad;
        d = p.x - tx; ad = fabsf(d); sl1 += (ad < 1.f) ? 0.5f * d * d : ad - 0.5f;
        d = p.y - ty; ad = fabsf(d); sl1 += (ad < 1.f) ? 0.5f * d * d : ad - 0.5f;
        d = p.z - tw; ad = fabsf(d); sl1 += (ad < 1.f) ? 0.5f * d * d : ad - 0.5f;
        d = p.w - th; ad = fabsf(d); sl1 += (ad < 1.f) ? 0.5f * d * d : ad - 0.5f;
    }

    // cross entropy: lse - x[gl]
    const float* row = lab + tid * NC;         // stride 21 (odd) -> 2-way alias, free
    float m = row[0];
    #pragma unroll
    for (int c = 1; c < NC; ++c) m = fmaxf(m, row[c]);
    float s = 0.f;
    #pragma unroll
    for (int c = 0; c < NC; ++c) s += __expf(row[c] - m);
    const float lse = m + __logf(s);
    const float ce = fmaxf(lse - row[gl], 0.f);   // >=0, bits order-monotonic

    const bool pos = gl > 0;
    ce_neg[idx] = pos ? 0.f : ce;              // coalesced

    // per-block positive stats (~5 pos threads): LDS atomics, then plain stores
    if (pos) {
        const int seg = (b - b0) * 4;          // 0 or 4
        atomicAdd(&st[seg + 0], 1.f);
        atomicAdd(&st[seg + 1], sl1);
        atomicAdd(&st[seg + 2], ce);
    }
    __syncthreads();
    if (tid == 0) {
        partial[2 * blockIdx.x]     = make_float4(st[0], st[1], st[2], 0.f);
        partial[2 * blockIdx.x + 1] = make_float4(st[4], st[5], st[6], 0.f);
    }
}

// ===================== K2: per-batch exact top-k sum =====================
__global__ __launch_bounds__(1024) void k_select(
    const float* __restrict__ ce_neg, const float4* __restrict__ partial,
    double* __restrict__ flb, double* __restrict__ fll, int* __restrict__ fpn)
{
    __shared__ uint32_t vals[NN];              // 67200 B
    __shared__ uint32_t hist[4096];            // 16384 B
    __shared__ uint32_t h256[256];
    __shared__ float    s_stats[4];            // pos, sl1, ce
    __shared__ uint32_t s_cur;
    __shared__ int      s_need;
    __shared__ uint32_t wC[16], oC[16];
    __shared__ double   dpart[16];

    const int tid = threadIdx.x, lane = tid & 63, wid = tid >> 6;
    const int b = blockIdx.x;

    if (tid < 4) s_stats[tid] = 0.f;
    for (int i = tid; i < 4096; i += 1024) hist[i] = 0u;
    __syncthreads();

    // ---- reduce per-block partial stats for this batch (~67 entries) ----
    {
        const int js = (b * NN) / 256;
        const int je = ((b + 1) * NN - 1) / 256;
        if (tid <= je - js) {
            const int j = js + tid;
            const float4 p0 = partial[2 * j];
            const float4 p1 = partial[2 * j + 1];
            const int bj = (j * 256) / NN;
            float cp = 0.f, cs = 0.f, cc = 0.f;
            if (bj == b)     { cp += p0.x; cs += p0.y; cc += p0.z; }
            if (bj == b - 1) { cp += p1.x; cs += p1.y; cc += p1.z; }
            if (cp != 0.f) {
                atomicAdd(&s_stats[0], cp);
                atomicAdd(&s_stats[1], cs);
                atomicAdd(&s_stats[2], cc);
            }
        }
    }

    // ---- load CE bits to LDS + 4096-bin histogram (top 12 IEEE bits) ----
    const float* src = ce_neg + (size_t)b * NN;
    for (int i = tid; i < NN; i += 1024) {
        const uint32_t v = __float_as_uint(src[i]);
        vals[i] = v;
        atomicAdd(&hist[v >> 20], 1u);
    }
    __syncthreads();

    const int pos = (int)(s_stats[0] + 0.5f);
    int k = 3 * pos;                           // NEG_RATIO
    if (k > NN) k = NN;
    if (k < 1) k = 1;                          // pos==0 masked in k_final

    // ---- suffix scan (descending bins) -> boundary bin + rank ----
    uint32_t c4[4]; uint32_t cnt = 0;
    #pragma unroll
    for (int j = 0; j < 4; ++j) { c4[j] = hist[4095 - (4 * tid + j)]; cnt += c4[j]; }
    uint32_t ic = cnt;
    #pragma unroll
    for (int off = 1; off < 64; off <<= 1) {
        const uint32_t tc = __shfl_up(ic, off);
        if (lane >= off) ic += tc;
    }
    if (lane == 63) wC[wid] = ic;
    __syncthreads();
    if (tid == 0) { uint32_t r = 0; for (int w = 0; w < 16; ++w) { oC[w] = r; r += wC[w]; } }
    __syncthreads();
    const int exC = (int)(oC[wid] + ic - cnt);
    if (exC < k && k <= exC + (int)cnt) {      // exactly one thread
        int need = k - exC;
        #pragma unroll
        for (int j = 0; j < 4; ++j) {
            const int c = (int)c4[j];
            if (need <= c) {
                s_cur = (4095u - (uint32_t)(4 * tid + j)) << 20;
                s_need = need;
                break;
            }
            need -= c;
        }
    }
    __syncthreads();

    // ---- exact radix refine of low 20 bits: (shift,bins)=(12,256),(4,256),(0,16) ----
    #pragma unroll
    for (int p = 0; p < 3; ++p) {
        const int sh = (p == 0) ? 12 : (p == 1) ? 4 : 0;
        const uint32_t nb = (p == 2) ? 16u : 256u;
        const uint32_t bm = nb - 1u;
        const uint32_t msk = (p == 0) ? 0xFFF00000u : (p == 1) ? 0xFFFFF000u : 0xFFFFFFF0u;
        if (tid < 256) h256[tid] = 0u;
        __syncthreads();
        const uint32_t cur = s_cur;
        for (int i = tid; i < NN; i += 1024) {
            const uint32_t v = vals[i];
            if ((v & msk) == cur) atomicAdd(&h256[(v >> sh) & bm], 1u);
        }
        __syncthreads();
        if (tid == 0) {
            int need = s_need;
            for (int d = (int)nb - 1; d >= 0; --d) {
                const int c = (int)h256[d];
                if (need <= c) { s_cur = cur | ((uint32_t)d << sh); s_need = need; break; }
                need -= c;
            }
        }
        __syncthreads();
    }

    // ---- tie-exact top-k sum: sum(v > T) + r*T ----
    const uint32_t T = s_cur;
    const int rf = s_need;
    double loc = 0.0;
    for (int i = tid; i < NN; i += 1024) {
        const uint32_t v = vals[i];
        if (v > T) loc += (double)__uint_as_float(v);
    }
    #pragma unroll
    for (int off = 32; off > 0; off >>= 1) loc += __shfl_down(loc, off);
    if (lane == 0) dpart[wid] = loc;
    __syncthreads();
    if (tid == 0) {
        double tot = 0.0;
        for (int w = 0; w < 16; ++w) tot += dpart[w];
        tot += (double)rf * (double)__uint_as_float(T);
        flb[b] = (double)s_stats[1];
        fll[b] = (double)s_stats[2] + tot;
        fpn[b] = pos;
    }
}

// ===================== K3: final reduction over B =====================
__global__ __launch_bounds__(64) void k_final(
    const double* __restrict__ flb, const double* __restrict__ fll,
    const int* __restrict__ fpn, float* __restrict__ out)
{
    const int t = threadIdx.x;                 // 64 == NB
    const double lb = flb[t];
    const double ll = fll[t];
    const int pn = fpn[t];
    const double nm = (pn > 0) ? 1.0 : 0.0;
    const float pf = fmaxf((float)pn, FP32_EPS_F);
    const double inv = nm / (double)pf;
    double tb = lb * inv;
    double tl = ll * inv;
    double tt = tb + tl;                       // COEFF = (1,1)
    #pragma unroll
    for (int off = 32; off > 0; off >>= 1) {
        tt += __shfl_down(tt, off);
        tb += __shfl_down(tb, off);
        tl += __shfl_down(tl, off);
    }
    if (t == 0) {
        out[0] = (float)(tt / (double)NB);
        out[1] = (float)(tb / (double)NB);
        out[2] = (float)(tl / (double)NB);
    }
}

// ===================== launcher =====================
extern "C" void kernel_launch(void* const* d_in, const int* in_sizes, int n_in,
                              void* d_out, int out_size, void* d_ws, size_t ws_size,
                              hipStream_t stream)
{
    const float* p_bboxs  = (const float*)d_in[0];
    const float* g_bboxs  = (const float*)d_in[1];
    const float* p_labels = (const float*)d_in[2];
    const int*   g_labels = (const int*)d_in[3];
    const float* ancs     = (const float*)d_in[4];
    float* out = (float*)d_out;

    char* ws = (char*)d_ws;
    float4* partial = (float4*)(ws + OFF_PARTIAL);
    double* flb     = (double*)(ws + OFF_FLB);
    double* fll     = (double*)(ws + OFF_FLL);
    int*    fpn     = (int*)   (ws + OFF_FPN);
    float*  ce_neg  = (float*) (ws + OFF_CENEG);

    // no memset needed: every workspace byte read is written first (no atomics)

    k_perdata<<<NBLK1, 256, 0, stream>>>(
        p_bboxs, g_bboxs, p_labels, g_labels, ancs, ce_neg, partial);

    k_select<<<NB, 1024, 0, stream>>>(ce_neg, partial, flb, fll, fpn);

    k_final<<<1, 64, 0, stream>>>(flb, fll, fpn, out);
}